// Round 1
// baseline (502.289 us; speedup 1.0000x reference)
//
#include <hip/hip_runtime.h>
#include <hip/hip_bf16.h>

#define BATCH 4
#define SEQ   2048
#define DIM   1024
#define NHEAD 16
#define HDIM  64

typedef __bf16  bf16x8 __attribute__((ext_vector_type(8)));
typedef float   f32x4  __attribute__((ext_vector_type(4)));

__device__ __forceinline__ __hip_bfloat16 f2bf(float x) { return __float2bfloat16(x); }

// ---------------------------------------------------------------------------
// C[M,N] = bf16(A[M,K]) * bf16(W[K,N]) + bias ; fp32 accumulate.
// 128x128 tile, BK=32, 256 threads = 4 waves (2x2), each wave 64x64 (4x4 MFMA frags).
// ---------------------------------------------------------------------------
template<typename TIN, typename TOUT>
__global__ __launch_bounds__(256)
void gemm_bias(const TIN* __restrict__ A, const float* __restrict__ W,
               const float* __restrict__ bias, TOUT* __restrict__ C,
               int M, int N, int K)
{
  constexpr int BM = 128, BN = 128, BK = 32, PAD = 8;
  __shared__ __align__(16) __hip_bfloat16 As[BM][BK + PAD];   // [row][k]
  __shared__ __align__(16) __hip_bfloat16 Bs[BN][BK + PAD];   // [col][k] (transposed)

  const int tid  = threadIdx.x;
  const int lane = tid & 63;
  const int wv   = tid >> 6;
  const int wm   = wv >> 1, wn = wv & 1;
  const int lg   = lane >> 4, lr = lane & 15;
  const int m0   = blockIdx.y * BM;
  const int n0   = blockIdx.x * BN;

  f32x4 acc[4][4] = {};

  for (int k0 = 0; k0 < K; k0 += BK) {
    // ---- stage A -> bf16 LDS ----
    if constexpr (sizeof(TIN) == 4) {
      #pragma unroll
      for (int p = 0; p < 4; ++p) {
        const int row = (tid >> 3) + p * 32;
        const int col = (tid & 7) * 4;
        const float4 vv = *reinterpret_cast<const float4*>(&A[(size_t)(m0 + row) * K + k0 + col]);
        As[row][col + 0] = f2bf(vv.x);
        As[row][col + 1] = f2bf(vv.y);
        As[row][col + 2] = f2bf(vv.z);
        As[row][col + 3] = f2bf(vv.w);
      }
    } else {
      #pragma unroll
      for (int p = 0; p < 2; ++p) {
        const int row = (tid >> 2) + p * 64;
        const int col = (tid & 3) * 8;
        *reinterpret_cast<uint4*>(&As[row][col]) =
            *reinterpret_cast<const uint4*>(&A[(size_t)(m0 + row) * K + k0 + col]);
      }
    }
    // ---- stage B transposed -> bf16 LDS ----
    {
      const int kk = tid >> 3;            // 0..31
      const int cb = (tid & 7) * 16;      // 0..112
      #pragma unroll
      for (int j = 0; j < 4; ++j) {
        const float4 vv = *reinterpret_cast<const float4*>(&W[(size_t)(k0 + kk) * N + n0 + cb + j * 4]);
        Bs[cb + j * 4 + 0][kk] = f2bf(vv.x);
        Bs[cb + j * 4 + 1][kk] = f2bf(vv.y);
        Bs[cb + j * 4 + 2][kk] = f2bf(vv.z);
        Bs[cb + j * 4 + 3][kk] = f2bf(vv.w);
      }
    }
    __syncthreads();

    bf16x8 af[4], bfr[4];
    #pragma unroll
    for (int m = 0; m < 4; ++m)
      af[m] = *reinterpret_cast<const bf16x8*>(&As[wm * 64 + m * 16 + lr][lg * 8]);
    #pragma unroll
    for (int n = 0; n < 4; ++n)
      bfr[n] = *reinterpret_cast<const bf16x8*>(&Bs[wn * 64 + n * 16 + lr][lg * 8]);
    #pragma unroll
    for (int m = 0; m < 4; ++m)
      #pragma unroll
      for (int n = 0; n < 4; ++n)
        acc[m][n] = __builtin_amdgcn_mfma_f32_16x16x32_bf16(af[m], bfr[n], acc[m][n], 0, 0, 0);
    __syncthreads();
  }

  // epilogue: D layout col = lane&15, row = 4*(lane>>4)+reg
  #pragma unroll
  for (int n = 0; n < 4; ++n) {
    const int col = n0 + wn * 64 + n * 16 + lr;
    const float bv = bias[col];
    #pragma unroll
    for (int m = 0; m < 4; ++m) {
      const int row = m0 + wm * 64 + m * 16 + lg * 4;
      #pragma unroll
      for (int r = 0; r < 4; ++r) {
        const float val = acc[m][n][r] + bv;
        if constexpr (sizeof(TOUT) == 2)
          C[(size_t)(row + r) * N + col] = f2bf(val);
        else
          C[(size_t)(row + r) * N + col] = val;
      }
    }
  }
}

// ---------------------------------------------------------------------------
// Flash attention: per (qblock of 64 rows, head, batch). 4 waves, each 16 q-rows.
// Online softmax, fp32 O-accumulators, all matmuls via 16x16x32 bf16 MFMA.
// ---------------------------------------------------------------------------
__global__ __launch_bounds__(256)
void flash_attn(const __hip_bfloat16* __restrict__ Qb,
                const __hip_bfloat16* __restrict__ Kb,
                const __hip_bfloat16* __restrict__ Vb,
                __hip_bfloat16* __restrict__ Ob)
{
  constexpr int QB = 64, KB = 64, PAD = 8;
  __shared__ __align__(16) __hip_bfloat16 Ks [KB][HDIM + PAD];   // [key][depth]
  __shared__ __align__(16) __hip_bfloat16 Vts[HDIM][KB + PAD];   // [depth][key]
  __shared__ __align__(16) __hip_bfloat16 Ps [QB][KB + PAD];     // [qrow][key]

  const int qb = blockIdx.x, h = blockIdx.y, b = blockIdx.z;
  const int tid  = threadIdx.x;
  const int lane = tid & 63, wv = tid >> 6;
  const int lg = lane >> 4, lr = lane & 15;

  // Q fragments held in registers for the whole block (A-operand: row=lane&15, k=8*(lane>>4)+reg)
  bf16x8 qf[2];
  {
    const size_t g = (size_t)((b * SEQ) + qb * QB + wv * 16 + lr) * DIM + h * HDIM;
    qf[0] = *reinterpret_cast<const bf16x8*>(&Qb[g + lg * 8]);
    qf[1] = *reinterpret_cast<const bf16x8*>(&Qb[g + 32 + lg * 8]);
  }

  float m_run[4] = {-INFINITY, -INFINITY, -INFINITY, -INFINITY};
  float l_run[4] = {0.f, 0.f, 0.f, 0.f};
  f32x4 accO[4] = {};

  for (int kb = 0; kb < SEQ; kb += KB) {
    // ---- stage K (row-major) and V (transposed) ----
    {
      const int row = tid >> 2;            // 0..63 (key index)
      const int cb  = (tid & 3) * 16;      // depth base 0/16/32/48
      const size_t g = (size_t)((b * SEQ) + kb + row) * DIM + h * HDIM + cb;
      *reinterpret_cast<uint4*>(&Ks[row][cb])     = *reinterpret_cast<const uint4*>(&Kb[g]);
      *reinterpret_cast<uint4*>(&Ks[row][cb + 8]) = *reinterpret_cast<const uint4*>(&Kb[g + 8]);
      __hip_bfloat16 tmp[16];
      *reinterpret_cast<uint4*>(&tmp[0]) = *reinterpret_cast<const uint4*>(&Vb[g]);
      *reinterpret_cast<uint4*>(&tmp[8]) = *reinterpret_cast<const uint4*>(&Vb[g + 8]);
      #pragma unroll
      for (int j = 0; j < 16; ++j) Vts[cb + j][row] = tmp[j];
    }
    __syncthreads();

    // ---- S = Q K^T * scale  (wave strip: 16 q-rows x 64 keys) ----
    float s[4][4];   // [col-frag][reg]
    #pragma unroll
    for (int c = 0; c < 4; ++c) {
      f32x4 sf = {};
      const bf16x8 kf0 = *reinterpret_cast<const bf16x8*>(&Ks[c * 16 + lr][lg * 8]);
      const bf16x8 kf1 = *reinterpret_cast<const bf16x8*>(&Ks[c * 16 + lr][32 + lg * 8]);
      sf = __builtin_amdgcn_mfma_f32_16x16x32_bf16(qf[0], kf0, sf, 0, 0, 0);
      sf = __builtin_amdgcn_mfma_f32_16x16x32_bf16(qf[1], kf1, sf, 0, 0, 0);
      #pragma unroll
      for (int r = 0; r < 4; ++r) s[c][r] = sf[r] * 0.125f;
    }

    // ---- online softmax; row r lives on the 16-lane group (row = 4*lg + r) ----
    #pragma unroll
    for (int r = 0; r < 4; ++r) {
      float mx = fmaxf(fmaxf(s[0][r], s[1][r]), fmaxf(s[2][r], s[3][r]));
      mx = fmaxf(mx, __shfl_xor(mx, 1));
      mx = fmaxf(mx, __shfl_xor(mx, 2));
      mx = fmaxf(mx, __shfl_xor(mx, 4));
      mx = fmaxf(mx, __shfl_xor(mx, 8));
      const float mnew  = fmaxf(m_run[r], mx);
      const float alpha = __expf(m_run[r] - mnew);   // 0 on first tile
      m_run[r] = mnew;
      float rs = 0.f;
      #pragma unroll
      for (int c = 0; c < 4; ++c) {
        const float p = __expf(s[c][r] - mnew);
        s[c][r] = p;
        rs += p;
      }
      rs += __shfl_xor(rs, 1);
      rs += __shfl_xor(rs, 2);
      rs += __shfl_xor(rs, 4);
      rs += __shfl_xor(rs, 8);
      l_run[r] = l_run[r] * alpha + rs;
      #pragma unroll
      for (int d = 0; d < 4; ++d) accO[d][r] *= alpha;
    }

    // ---- stage P (D-layout -> LDS row-major) ----
    #pragma unroll
    for (int c = 0; c < 4; ++c)
      #pragma unroll
      for (int r = 0; r < 4; ++r)
        Ps[wv * 16 + lg * 4 + r][c * 16 + lr] = f2bf(s[c][r]);
    __syncthreads();

    // ---- O += P V ----
    #pragma unroll
    for (int ks = 0; ks < 2; ++ks) {
      const bf16x8 pf = *reinterpret_cast<const bf16x8*>(&Ps[wv * 16 + lr][ks * 32 + lg * 8]);
      #pragma unroll
      for (int d = 0; d < 4; ++d) {
        const bf16x8 vf = *reinterpret_cast<const bf16x8*>(&Vts[d * 16 + lr][ks * 32 + lg * 8]);
        accO[d] = __builtin_amdgcn_mfma_f32_16x16x32_bf16(pf, vf, accO[d], 0, 0, 0);
      }
    }
    __syncthreads();
  }

  // ---- write O / l ----
  #pragma unroll
  for (int r = 0; r < 4; ++r) {
    const float inv = 1.f / l_run[r];
    const size_t row = (size_t)(b * SEQ) + qb * QB + wv * 16 + lg * 4 + r;
    #pragma unroll
    for (int d = 0; d < 4; ++d)
      Ob[row * DIM + h * HDIM + d * 16 + lr] = f2bf(accO[d][r] * inv);
  }
}

// ---------------------------------------------------------------------------
extern "C" void kernel_launch(void* const* d_in, const int* in_sizes, int n_in,
                              void* d_out, int out_size, void* d_ws, size_t ws_size,
                              hipStream_t stream)
{
  const float* q  = (const float*)d_in[0];
  const float* k  = (const float*)d_in[1];
  const float* v  = (const float*)d_in[2];
  const float* wq = (const float*)d_in[3];
  const float* bq = (const float*)d_in[4];
  const float* wk = (const float*)d_in[5];
  const float* bk = (const float*)d_in[6];
  const float* wv = (const float*)d_in[7];
  const float* bv = (const float*)d_in[8];
  const float* wo = (const float*)d_in[9];
  const float* bo = (const float*)d_in[10];

  const int M = BATCH * SEQ, N = DIM, K = DIM;

  __hip_bfloat16* Qb = (__hip_bfloat16*)d_ws;            // 16 MB each
  __hip_bfloat16* Kb = Qb + (size_t)M * N;
  __hip_bfloat16* Vb = Kb + (size_t)M * N;
  __hip_bfloat16* Ob = Vb + (size_t)M * N;

  dim3 ggrid(N / 128, M / 128);   // (8, 64)
  gemm_bias<float, __hip_bfloat16><<<ggrid, 256, 0, stream>>>(q, wq, bq, Qb, M, N, K);
  gemm_bias<float, __hip_bfloat16><<<ggrid, 256, 0, stream>>>(k, wk, bk, Kb, M, N, K);
  gemm_bias<float, __hip_bfloat16><<<ggrid, 256, 0, stream>>>(v, wv, bv, Vb, M, N, K);

  dim3 agrid(SEQ / 64, NHEAD, BATCH);
  flash_attn<<<agrid, 256, 0, stream>>>(Qb, Kb, Vb, Ob);

  gemm_bias<__hip_bfloat16, float><<<ggrid, 256, 0, stream>>>(Ob, wo, bo, (float*)d_out, M, N, K);
}

// Round 3
// 421.928 us; speedup vs baseline: 1.1905x; 1.1905x over previous
//
#include <hip/hip_runtime.h>
#include <hip/hip_bf16.h>

#define BATCH 4
#define SEQ   2048
#define DIM   1024
#define NHEAD 16
#define HDIM  64

typedef __bf16    bf16x8 __attribute__((ext_vector_type(8)));
typedef float     f32x16 __attribute__((ext_vector_type(16)));
typedef unsigned  u32;

__device__ __forceinline__ unsigned short f2bfu(float x) {
  union { __hip_bfloat16 b; unsigned short u; } c; c.b = __float2bfloat16(x); return c.u;
}
__device__ __forceinline__ u32 cvtpk(float lo, float hi) {
  u32 r; asm("v_cvt_pk_bf16_f32 %0, %1, %2" : "=v"(r) : "v"(lo), "v"(hi)); return r;
}

// ---------------------------------------------------------------------------
// GEMM: C[M,N] = bf16(A) * bf16(W) + bias. 128x128 tile, BK=64, 4 waves (2x2),
// 32x32x16 MFMA, double-buffered XOR-swizzled LDS, async load/store split.
// ---------------------------------------------------------------------------
template<typename TIN, typename TOUT>
__global__ __launch_bounds__(256)
void gemm_bias(const TIN* __restrict__ A, const float* __restrict__ W,
               const float* __restrict__ bias, TOUT* __restrict__ C,
               int M, int N, int K)
{
  __shared__ __align__(16) u32 As32[2][128][32];   // bf16 pairs along k, 128B rows
  __shared__ __align__(16) u32 Bs32[2][128][32];   // [ncol][k-pairs]

  // XCD swizzle: same-by row band -> same XCD. 512 blocks = 8 xcd * 8 bx * 8 byhi
  const int id  = blockIdx.x;
  const int xcd = id & 7;
  const int rr  = id >> 3;
  const int bx  = rr & 7;
  const int by  = xcd + 8 * (rr >> 3);
  const int m0 = by * 128, n0 = bx * 128;

  const int tid = threadIdx.x;
  const int lane = tid & 63, wv = tid >> 6;
  const int l31 = lane & 31, hi = lane >> 5;
  const int wm = wv >> 1, wn = wv & 1;

  const int NT = K / 64;

  f32x16 acc[2][2] = {};

  // staging thread mapping
  const int arow = tid >> 1;            // A row 0..127
  const int acol = (tid & 1) * 32;      // A k-element base
  const int nb   = tid & 31;            // B col group (4 cols)
  const int kr   = tid >> 5;            // B row group (8 k-rows)

  float4 ald[8];        // fp32 A staging
  uint4  aldb[4];       // bf16 A staging
  float4 bld[8];        // W staging

  auto load_t = [&](int t) {
    const int k0 = t * 64;
    if constexpr (sizeof(TIN) == 4) {
      #pragma unroll
      for (int j = 0; j < 8; ++j)
        ald[j] = *reinterpret_cast<const float4*>(&A[(size_t)(m0 + arow) * K + k0 + acol + j * 4]);
    } else {
      #pragma unroll
      for (int j = 0; j < 4; ++j)
        aldb[j] = *reinterpret_cast<const uint4*>(&A[(size_t)(m0 + arow) * K + k0 + acol + j * 8]);
    }
    #pragma unroll
    for (int j = 0; j < 8; ++j)
      bld[j] = *reinterpret_cast<const float4*>(&W[(size_t)(k0 + kr * 8 + j) * N + n0 + nb * 4]);
  };

  auto store_t = [&](int bb) {
    // ---- A ----
    u32 apack[16];
    if constexpr (sizeof(TIN) == 4) {
      #pragma unroll
      for (int j = 0; j < 8; ++j) {
        apack[j * 2 + 0] = cvtpk(ald[j].x, ald[j].y);
        apack[j * 2 + 1] = cvtpk(ald[j].z, ald[j].w);
      }
    } else {
      #pragma unroll
      for (int j = 0; j < 4; ++j) {
        apack[j * 4 + 0] = aldb[j].x; apack[j * 4 + 1] = aldb[j].y;
        apack[j * 4 + 2] = aldb[j].z; apack[j * 4 + 3] = aldb[j].w;
      }
    }
    const int sw = (arow & 7) << 2;
    #pragma unroll
    for (int q = 0; q < 4; ++q) {
      const int idx = (((tid & 1) * 16) + q * 4) ^ sw;
      *reinterpret_cast<uint4*>(&As32[bb][arow][idx]) =
        make_uint4(apack[q*4+0], apack[q*4+1], apack[q*4+2], apack[q*4+3]);
    }
    // ---- B (transpose-pack: pairs along k per col) ----
    u32 bpack[4][4];
    #pragma unroll
    for (int p = 0; p < 4; ++p) {
      const float4 v0 = bld[2 * p], v1 = bld[2 * p + 1];
      bpack[0][p] = cvtpk(v0.x, v1.x);
      bpack[1][p] = cvtpk(v0.y, v1.y);
      bpack[2][p] = cvtpk(v0.z, v1.z);
      bpack[3][p] = cvtpk(v0.w, v1.w);
    }
    #pragma unroll
    for (int c = 0; c < 4; ++c) {
      const int cu  = (c + nb) & 3;               // rotate to spread banks
      const int col = nb * 4 + cu;
      const int idx = (kr * 4) ^ ((col & 7) << 2);
      *reinterpret_cast<uint4*>(&Bs32[bb][col][idx]) =
        make_uint4(bpack[cu][0], bpack[cu][1], bpack[cu][2], bpack[cu][3]);
    }
  };

  load_t(0); store_t(0); __syncthreads();

  for (int t = 0; t < NT; ++t) {
    const int bb = t & 1;
    if (t + 1 < NT) load_t(t + 1);
    #pragma unroll
    for (int kk = 0; kk < 4; ++kk) {
      bf16x8 af[2], bfv[2];
      #pragma unroll
      for (int mi = 0; mi < 2; ++mi) {
        const int row = wm * 64 + mi * 32 + l31;
        const int idx = (kk * 8 + hi * 4) ^ ((row & 7) << 2);
        af[mi] = *reinterpret_cast<const bf16x8*>(&As32[bb][row][idx]);
      }
      #pragma unroll
      for (int ni = 0; ni < 2; ++ni) {
        const int col = wn * 64 + ni * 32 + l31;
        const int idx = (kk * 8 + hi * 4) ^ ((col & 7) << 2);
        bfv[ni] = *reinterpret_cast<const bf16x8*>(&Bs32[bb][col][idx]);
      }
      #pragma unroll
      for (int mi = 0; mi < 2; ++mi)
        #pragma unroll
        for (int ni = 0; ni < 2; ++ni)
          acc[mi][ni] = __builtin_amdgcn_mfma_f32_32x32x16_bf16(af[mi], bfv[ni], acc[mi][ni], 0, 0, 0);
    }
    if (t + 1 < NT) store_t(bb ^ 1);
    __syncthreads();
  }

  // epilogue: D col = lane&31, row = (r&3) + 8*(r>>2) + 4*hi
  #pragma unroll
  for (int ni = 0; ni < 2; ++ni) {
    const int col = n0 + wn * 64 + ni * 32 + l31;
    const float bv = bias[col];
    #pragma unroll
    for (int mi = 0; mi < 2; ++mi) {
      #pragma unroll
      for (int g = 0; g < 4; ++g)
        #pragma unroll
        for (int e = 0; e < 4; ++e) {
          const int row = m0 + wm * 64 + mi * 32 + g * 8 + hi * 4 + e;
          const float val = acc[mi][ni][g * 4 + e] + bv;
          if constexpr (sizeof(TOUT) == 2)
            C[(size_t)row * N + col] = __float2bfloat16(val);
          else
            C[(size_t)row * N + col] = val;
        }
    }
  }
}

// ---------------------------------------------------------------------------
// Flash attention. QB=128 (4 waves x 32 q-rows), KB=64. Swapped MFMAs:
// S^T = mfma(K, Q), O^T = mfma(V^T, P^T). In-register softmax, cvt_pk +
// permlane32_swap for P fragments. Double-buffered swizzled LDS for K and
// u32-packed transposed V.
// ---------------------------------------------------------------------------
__global__ __launch_bounds__(256)
void flash_attn(const __hip_bfloat16* __restrict__ Qb,
                const __hip_bfloat16* __restrict__ Kb,
                const __hip_bfloat16* __restrict__ Vb,
                __hip_bfloat16* __restrict__ Ob)
{
  __shared__ __align__(16) u32 Ks32[2][64][32];  // K tile, bf16 pairs along depth
  __shared__ __align__(16) u32 Vt32[2][64][32];  // V^T tile: [depth][key-pair]

  // XCD swizzle: 1024 blocks = 8 xcd * 128 ; h = xcd + 8*hh
  const int id  = blockIdx.x;
  const int xcd = id & 7;
  const int kk_ = id >> 3;
  const int qb  = kk_ & 15;
  const int hh  = (kk_ >> 4) & 1;
  const int b   = kk_ >> 5;
  const int h   = xcd + 8 * hh;

  const int tid = threadIdx.x, lane = tid & 63, wv = tid >> 6;
  const int l31 = lane & 31, hi = lane >> 5;

  const size_t headoff = (size_t)h * HDIM;
  const int gq = b * SEQ + qb * 128 + wv * 32 + l31;

  // Q fragments (B-operand: col=l31=qrow, k=depth)
  bf16x8 qf[4];
  #pragma unroll
  for (int dk = 0; dk < 4; ++dk)
    qf[dk] = *reinterpret_cast<const bf16x8*>(&Qb[(size_t)gq * DIM + headoff + dk * 16 + hi * 8]);

  f32x16 accO[2] = {};
  float m_run = -1e30f, l_run = 0.f;

  // staging mappings
  const int skey = tid >> 2;     // K: key row 0..63
  const int sdq  = tid & 3;      // K: depth quarter
  const int vkp  = tid >> 3;     // V: key pair 0..31
  const int vdb  = tid & 7;      // V: depth block 0..7
  const size_t kbase = (size_t)b * SEQ * DIM + headoff;

  uint4 kst[2], vst[2];
  auto load_t = [&](int t) {
    const int kb = t * 64;
    const __hip_bfloat16* kp_ = &Kb[kbase + (size_t)(kb + skey) * DIM + sdq * 16];
    kst[0] = *reinterpret_cast<const uint4*>(kp_);
    kst[1] = *reinterpret_cast<const uint4*>(kp_ + 8);
    const __hip_bfloat16* vp_ = &Vb[kbase + (size_t)(kb + vkp * 2) * DIM + vdb * 8];
    vst[0] = *reinterpret_cast<const uint4*>(vp_);
    vst[1] = *reinterpret_cast<const uint4*>(vp_ + DIM);
  };
  auto store_t = [&](int bb) {
    const int sw = (skey & 7) << 2;
    *reinterpret_cast<uint4*>(&Ks32[bb][skey][(sdq * 8 + 0) ^ sw]) = kst[0];
    *reinterpret_cast<uint4*>(&Ks32[bb][skey][(sdq * 8 + 4) ^ sw]) = kst[1];
    const unsigned short* a  = (const unsigned short*)&vst[0];
    const unsigned short* bv = (const unsigned short*)&vst[1];
    #pragma unroll
    for (int j = 0; j < 8; ++j) {
      const int row = vdb * 8 + j;                 // row&7 == j
      Vt32[bb][row][vkp ^ (j << 2)] = (u32)a[j] | ((u32)bv[j] << 16);
    }
  };

  load_t(0); store_t(0); __syncthreads();

  const float C1 = 0.125f * 1.44269504f;   // scale * log2(e)

  for (int t = 0; t < SEQ / 64; ++t) {
    const int bb = t & 1;
    if (t < SEQ / 64 - 1) load_t(t + 1);

    // ---- S^T = K * Q^T ----
    f32x16 sacc[2] = {};
    #pragma unroll
    for (int kt = 0; kt < 2; ++kt) {
      const int row = kt * 32 + l31;
      const int sw = (row & 7) << 2;
      #pragma unroll
      for (int dk = 0; dk < 4; ++dk) {
        bf16x8 kf = *reinterpret_cast<const bf16x8*>(&Ks32[bb][row][(dk * 8 + hi * 4) ^ sw]);
        sacc[kt] = __builtin_amdgcn_mfma_f32_32x32x16_bf16(kf, qf[dk], sacc[kt], 0, 0, 0);
      }
    }

    // ---- online softmax (q-row = l31 for all 32 values) ----
    float mx = sacc[0][0];
    #pragma unroll
    for (int r_ = 1; r_ < 16; ++r_) mx = fmaxf(mx, sacc[0][r_]);
    #pragma unroll
    for (int r_ = 0; r_ < 16; ++r_) mx = fmaxf(mx, sacc[1][r_]);
    mx = fmaxf(mx, __shfl_xor(mx, 32));
    const float mnew  = fmaxf(m_run, mx * 0.125f);
    const float alpha = __builtin_amdgcn_exp2f((m_run - mnew) * 1.44269504f);
    m_run = mnew;
    const float C2 = -mnew * 1.44269504f;

    float p0[16], p1[16];
    float rs = 0.f;
    #pragma unroll
    for (int r_ = 0; r_ < 16; ++r_) { p0[r_] = __builtin_amdgcn_exp2f(fmaf(sacc[0][r_], C1, C2)); rs += p0[r_]; }
    #pragma unroll
    for (int r_ = 0; r_ < 16; ++r_) { p1[r_] = __builtin_amdgcn_exp2f(fmaf(sacc[1][r_], C1, C2)); rs += p1[r_]; }
    rs += __shfl_xor(rs, 32);
    l_run = l_run * alpha + rs;
    accO[0] *= alpha;
    accO[1] *= alpha;

    // ---- P fragments via cvt_pk + permlane32_swap ----
    // P value p[r] (r=0..15) sits at key crow(r,hi) = (r&3) + 8*(r>>2) + 4*hi.
    // B-operand needs word j = keys (8*hi + 2j, 8*hi + 2j + 1) per 16-key window.
    // swap(vdst,vsrc) -> {new_vdst={vdst_lo,vsrc_lo}, new_vsrc={vdst_hi,vsrc_hi}}:
    //   s1 = swap(cvtpk(P0,P1), cvtpk(P4,P5)) -> word0 = s1[0], word2 = s1[1]
    //   s2 = swap(cvtpk(P2,P3), cvtpk(P6,P7)) -> word1 = s2[0], word3 = s2[1]
    u32 pf[4][4];
#define MAKE_PF(DST, P, B) do {                                            \
      u32 x1 = cvtpk(P[B+0], P[B+1]);                                      \
      u32 y1 = cvtpk(P[B+4], P[B+5]);                                      \
      u32 x2 = cvtpk(P[B+2], P[B+3]);                                      \
      u32 y2 = cvtpk(P[B+6], P[B+7]);                                      \
      auto s1 = __builtin_amdgcn_permlane32_swap(x1, y1, false, false);    \
      auto s2 = __builtin_amdgcn_permlane32_swap(x2, y2, false, false);    \
      DST[0] = (u32)s1[0]; DST[1] = (u32)s2[0];                            \
      DST[2] = (u32)s1[1]; DST[3] = (u32)s2[1];                            \
    } while (0)
    MAKE_PF(pf[0], p0, 0);
    MAKE_PF(pf[1], p0, 8);
    MAKE_PF(pf[2], p1, 0);
    MAKE_PF(pf[3], p1, 8);
#undef MAKE_PF

    // ---- O^T += V^T * P^T ----
    #pragma unroll
    for (int dt = 0; dt < 2; ++dt) {
      const int row = dt * 32 + l31;
      const int sw = (row & 7) << 2;
      #pragma unroll
      for (int kf = 0; kf < 4; ++kf) {
        bf16x8 vf = *reinterpret_cast<const bf16x8*>(&Vt32[bb][row][(kf * 8 + hi * 4) ^ sw]);
        union { u32 u[4]; bf16x8 v; } pu;
        pu.u[0] = pf[kf][0]; pu.u[1] = pf[kf][1]; pu.u[2] = pf[kf][2]; pu.u[3] = pf[kf][3];
        accO[dt] = __builtin_amdgcn_mfma_f32_32x32x16_bf16(vf, pu.v, accO[dt], 0, 0, 0);
      }
    }

    if (t < SEQ / 64 - 1) store_t(bb ^ 1);
    __syncthreads();
  }

  // ---- write O (q-row = l31; depth = crow(r,hi) mapping) ----
  const float inv = 1.f / l_run;
  #pragma unroll
  for (int dt = 0; dt < 2; ++dt)
    #pragma unroll
    for (int g = 0; g < 4; ++g) {
      ushort4 o;
      o.x = f2bfu(accO[dt][g * 4 + 0] * inv);
      o.y = f2bfu(accO[dt][g * 4 + 1] * inv);
      o.z = f2bfu(accO[dt][g * 4 + 2] * inv);
      o.w = f2bfu(accO[dt][g * 4 + 3] * inv);
      *reinterpret_cast<ushort4*>(&Ob[(size_t)gq * DIM + headoff + dt * 32 + g * 8 + hi * 4]) = o;
    }
}

// ---------------------------------------------------------------------------
extern "C" void kernel_launch(void* const* d_in, const int* in_sizes, int n_in,
                              void* d_out, int out_size, void* d_ws, size_t ws_size,
                              hipStream_t stream)
{
  const float* q  = (const float*)d_in[0];
  const float* k  = (const float*)d_in[1];
  const float* v  = (const float*)d_in[2];
  const float* wq = (const float*)d_in[3];
  const float* bq = (const float*)d_in[4];
  const float* wk = (const float*)d_in[5];
  const float* bk = (const float*)d_in[6];
  const float* wv = (const float*)d_in[7];
  const float* bv = (const float*)d_in[8];
  const float* wo = (const float*)d_in[9];
  const float* bo = (const float*)d_in[10];

  const int M = BATCH * SEQ, N = DIM, K = DIM;

  __hip_bfloat16* Qb = (__hip_bfloat16*)d_ws;
  __hip_bfloat16* Kb = Qb + (size_t)M * N;
  __hip_bfloat16* Vb = Kb + (size_t)M * N;
  __hip_bfloat16* Ob = Vb + (size_t)M * N;

  gemm_bias<float, __hip_bfloat16><<<512, 256, 0, stream>>>(q, wq, bq, Qb, M, N, K);
  gemm_bias<float, __hip_bfloat16><<<512, 256, 0, stream>>>(k, wk, bk, Kb, M, N, K);
  gemm_bias<float, __hip_bfloat16><<<512, 256, 0, stream>>>(v, wv, bv, Vb, M, N, K);

  flash_attn<<<1024, 256, 0, stream>>>(Qb, Kb, Vb, Ob);

  gemm_bias<__hip_bfloat16, float><<<512, 256, 0, stream>>>(Ob, wo, bo, (float*)d_out, M, N, K);
}

// Round 4
// 314.942 us; speedup vs baseline: 1.5949x; 1.3397x over previous
//
#include <hip/hip_runtime.h>
#include <hip/hip_bf16.h>

#define BATCH 4
#define SEQ   2048
#define DIM   1024
#define NHEAD 16
#define HDIM  64

typedef __bf16    bf16x8 __attribute__((ext_vector_type(8)));
typedef float     f32x16 __attribute__((ext_vector_type(16)));
typedef unsigned  u32;

__device__ __forceinline__ unsigned short f2bfu(float x) {
  union { __hip_bfloat16 b; unsigned short u; } c; c.b = __float2bfloat16(x); return c.u;
}
__device__ __forceinline__ u32 cvtpk(float lo, float hi) {
  u32 r; asm("v_cvt_pk_bf16_f32 %0, %1, %2" : "=v"(r) : "v"(lo), "v"(hi)); return r;
}
__device__ __forceinline__ float max3f(float a, float b, float c) {
  float r; asm("v_max3_f32 %0, %1, %2, %3" : "=v"(r) : "v"(a), "v"(b), "v"(c)); return r;
}
// unified LDS swizzle: distinct for rows differing in bits 0-2 OR bits 3-5
__device__ __forceinline__ int swz4(int row) {
  return ((row & 7) ^ ((row >> 3) & 7)) << 2;
}

// ---------------------------------------------------------------------------
// GEMM: C[M,N] = bf16(A) * bf16(W) + bias. 128x128 tile, BK=64, 4 waves (2x2),
// 32x32x16 MFMA, double-buffered swizzled LDS, reg-staged loads.
// ---------------------------------------------------------------------------
template<typename TIN, typename TOUT>
__global__ __launch_bounds__(256, 2)
void gemm_bias(const TIN* __restrict__ A, const float* __restrict__ W,
               const float* __restrict__ bias, TOUT* __restrict__ C,
               int M, int N, int K)
{
  __shared__ __align__(16) u32 As32[2][128][32];   // bf16 pairs along k, 128B rows
  __shared__ __align__(16) u32 Bs32[2][128][32];   // [ncol][k-pairs]

  // XCD swizzle: blocks sharing an A row-band land on one XCD
  const int id  = blockIdx.x;
  const int xcd = id & 7;
  const int rr  = id >> 3;
  const int bx  = rr & 7;
  const int by  = xcd + 8 * (rr >> 3);
  const int m0 = by * 128, n0 = bx * 128;

  const int tid = threadIdx.x;
  const int lane = tid & 63, wv = tid >> 6;
  const int l31 = lane & 31, hi = lane >> 5;
  const int wm = wv >> 1, wn = wv & 1;

  const int NT = K / 64;

  f32x16 acc[2][2] = {};

  // staging thread mapping (coalesced: 8 lanes cover 256B of one row)
  const int arow = tid >> 3;            // A row 0..31 (+p*32)
  const int acol = (tid & 7) * 8;       // A k-element base
  const int nb   = tid & 31;            // B col group (4 cols)
  const int kr   = tid >> 5;            // B row group (8 k-rows)

  float4 ald[4][2];     // fp32 A staging
  uint4  aldb[4];       // bf16 A staging
  float4 bld[8];        // W staging

  auto load_t = [&](int t) {
    const int k0 = t * 64;
    if constexpr (sizeof(TIN) == 4) {
      #pragma unroll
      for (int p = 0; p < 4; ++p) {
        const float* ap = &A[(size_t)(m0 + arow + p * 32) * K + k0 + acol];
        ald[p][0] = *reinterpret_cast<const float4*>(ap);
        ald[p][1] = *reinterpret_cast<const float4*>(ap + 4);
      }
    } else {
      #pragma unroll
      for (int p = 0; p < 4; ++p)
        aldb[p] = *reinterpret_cast<const uint4*>(&A[(size_t)(m0 + arow + p * 32) * K + k0 + acol]);
    }
    #pragma unroll
    for (int j = 0; j < 8; ++j)
      bld[j] = *reinterpret_cast<const float4*>(&W[(size_t)(k0 + kr * 8 + j) * N + n0 + nb * 4]);
  };

  auto store_t = [&](int bb) {
    // ---- A ----
    #pragma unroll
    for (int p = 0; p < 4; ++p) {
      const int row = arow + p * 32;
      const int idx = ((tid & 7) * 4) ^ ((row & 7) << 2);
      uint4 pk;
      if constexpr (sizeof(TIN) == 4) {
        pk.x = cvtpk(ald[p][0].x, ald[p][0].y);
        pk.y = cvtpk(ald[p][0].z, ald[p][0].w);
        pk.z = cvtpk(ald[p][1].x, ald[p][1].y);
        pk.w = cvtpk(ald[p][1].z, ald[p][1].w);
      } else {
        pk = aldb[p];
      }
      *reinterpret_cast<uint4*>(&As32[bb][row][idx]) = pk;
    }
    // ---- B (transpose-pack: pairs along k per col) ----
    u32 bpack[4][4];
    #pragma unroll
    for (int p = 0; p < 4; ++p) {
      const float4 v0 = bld[2 * p], v1 = bld[2 * p + 1];
      bpack[0][p] = cvtpk(v0.x, v1.x);
      bpack[1][p] = cvtpk(v0.y, v1.y);
      bpack[2][p] = cvtpk(v0.z, v1.z);
      bpack[3][p] = cvtpk(v0.w, v1.w);
    }
    #pragma unroll
    for (int c = 0; c < 4; ++c) {
      const int cu  = (c + nb) & 3;               // rotate to spread banks
      const int col = nb * 4 + cu;
      const int idx = (kr * 4) ^ ((col & 7) << 2);
      *reinterpret_cast<uint4*>(&Bs32[bb][col][idx]) =
        make_uint4(bpack[cu][0], bpack[cu][1], bpack[cu][2], bpack[cu][3]);
    }
  };

  load_t(0); store_t(0); __syncthreads();

  for (int t = 0; t < NT; ++t) {
    const int bb = t & 1;
    if (t + 1 < NT) load_t(t + 1);
    #pragma unroll
    for (int kk = 0; kk < 4; ++kk) {
      bf16x8 af[2], bfv[2];
      #pragma unroll
      for (int mi = 0; mi < 2; ++mi) {
        const int row = wm * 64 + mi * 32 + l31;
        const int idx = (kk * 8 + hi * 4) ^ ((row & 7) << 2);
        af[mi] = *reinterpret_cast<const bf16x8*>(&As32[bb][row][idx]);
      }
      #pragma unroll
      for (int ni = 0; ni < 2; ++ni) {
        const int col = wn * 64 + ni * 32 + l31;
        const int idx = (kk * 8 + hi * 4) ^ ((col & 7) << 2);
        bfv[ni] = *reinterpret_cast<const bf16x8*>(&Bs32[bb][col][idx]);
      }
      #pragma unroll
      for (int mi = 0; mi < 2; ++mi)
        #pragma unroll
        for (int ni = 0; ni < 2; ++ni)
          acc[mi][ni] = __builtin_amdgcn_mfma_f32_32x32x16_bf16(af[mi], bfv[ni], acc[mi][ni], 0, 0, 0);
    }
    if (t + 1 < NT) store_t(bb ^ 1);
    __syncthreads();
  }

  // epilogue: D col = lane&31, row = (r&3) + 8*(r>>2) + 4*hi
  #pragma unroll
  for (int ni = 0; ni < 2; ++ni) {
    const int col = n0 + wn * 64 + ni * 32 + l31;
    const float bv = bias[col];
    #pragma unroll
    for (int mi = 0; mi < 2; ++mi) {
      #pragma unroll
      for (int g = 0; g < 4; ++g)
        #pragma unroll
        for (int e = 0; e < 4; ++e) {
          const int row = m0 + wm * 64 + mi * 32 + g * 8 + hi * 4 + e;
          const float val = acc[mi][ni][g * 4 + e] + bv;
          if constexpr (sizeof(TOUT) == 2)
            C[(size_t)row * N + col] = __float2bfloat16(val);
          else
            C[(size_t)row * N + col] = val;
        }
    }
  }
}

// ---------------------------------------------------------------------------
// Flash attention. QB=256 (4 waves x 64 q-rows), KB=64. Each K/V LDS fragment
// feeds TWO q-half MFMAs (halved LDS read traffic). Swapped MFMAs:
// S^T = mfma(K, Q), O^T = mfma(V^T, P^T). In-register softmax (max3 tree,
// defer-rescale), cvt_pk + permlane32_swap P fragments. Unified swz4 swizzle.
// ---------------------------------------------------------------------------
__global__ __launch_bounds__(256, 2)
void flash_attn(const __hip_bfloat16* __restrict__ Qb,
                const __hip_bfloat16* __restrict__ Kb,
                const __hip_bfloat16* __restrict__ Vb,
                __hip_bfloat16* __restrict__ Ob)
{
  __shared__ __align__(16) u32 Ks32[2][64][32];  // K tile, bf16 pairs along depth
  __shared__ __align__(16) u32 Vt32[2][64][32];  // V^T tile: [depth][key-pair]

  // 512 blocks = 8 xcd * 8 qb * 2 hh * 4 b ; h = xcd + 8*hh (qb's of one head share an XCD L2)
  const int id  = blockIdx.x;
  const int xcd = id & 7;
  const int r_  = id >> 3;
  const int qb  = r_ & 7;
  const int hh  = (r_ >> 3) & 1;
  const int b   = r_ >> 4;
  const int h   = xcd + 8 * hh;

  const int tid = threadIdx.x, lane = tid & 63, wv = tid >> 6;
  const int l31 = lane & 31, hi = lane >> 5;

  const size_t headoff = (size_t)h * HDIM;
  const int q0 = b * SEQ + qb * 256 + wv * 64;

  // Q fragments (B-operand: col=l31=qrow, k=depth), two q-halves
  bf16x8 qf[2][4];
  #pragma unroll
  for (int qh = 0; qh < 2; ++qh)
    #pragma unroll
    for (int dk = 0; dk < 4; ++dk)
      qf[qh][dk] = *reinterpret_cast<const bf16x8*>(
        &Qb[(size_t)(q0 + qh * 32 + l31) * DIM + headoff + dk * 16 + hi * 8]);

  f32x16 accO[2][2] = {};
  float m_run[2] = {-1e30f, -1e30f}, l_run[2] = {0.f, 0.f};

  // staging mappings
  const int skey = tid >> 2;     // K: key row 0..63
  const int sdq  = tid & 3;      // K: depth quarter
  const int vkp  = tid >> 3;     // V: key pair 0..31
  const int vdb  = tid & 7;      // V: depth block 0..7
  const size_t kbase = (size_t)b * SEQ * DIM + headoff;

  uint4 kst[2], vst[2];
  auto load_t = [&](int t) {
    const int kb = t * 64;
    const __hip_bfloat16* kp_ = &Kb[kbase + (size_t)(kb + skey) * DIM + sdq * 16];
    kst[0] = *reinterpret_cast<const uint4*>(kp_);
    kst[1] = *reinterpret_cast<const uint4*>(kp_ + 8);
    const __hip_bfloat16* vp_ = &Vb[kbase + (size_t)(kb + vkp * 2) * DIM + vdb * 8];
    vst[0] = *reinterpret_cast<const uint4*>(vp_);
    vst[1] = *reinterpret_cast<const uint4*>(vp_ + DIM);
  };
  auto store_t = [&](int bb) {
    const int sk = swz4(skey);
    *reinterpret_cast<uint4*>(&Ks32[bb][skey][(sdq * 8 + 0) ^ sk]) = kst[0];
    *reinterpret_cast<uint4*>(&Ks32[bb][skey][(sdq * 8 + 4) ^ sk]) = kst[1];
    const unsigned short* a  = (const unsigned short*)&vst[0];
    const unsigned short* bv = (const unsigned short*)&vst[1];
    #pragma unroll
    for (int j = 0; j < 8; ++j) {
      const int row = vdb * 8 + j;
      Vt32[bb][row][vkp ^ swz4(row)] = (u32)a[j] | ((u32)bv[j] << 16);
    }
  };

  load_t(0); store_t(0); __syncthreads();

  const float C1  = 0.125f * 1.44269504f;   // scale * log2(e)
  const float L2E = 1.44269504f;

  for (int t = 0; t < SEQ / 64; ++t) {
    const int bb = t & 1;
    if (t < SEQ / 64 - 1) load_t(t + 1);

    // ---- S^T = K * Q^T ; each K fragment feeds both q-halves ----
    f32x16 sacc[2][2] = {};   // [qh][kt]
    #pragma unroll
    for (int kt = 0; kt < 2; ++kt) {
      const int row = kt * 32 + l31;
      const int sk = swz4(row);
      #pragma unroll
      for (int dk = 0; dk < 4; ++dk) {
        bf16x8 kf = *reinterpret_cast<const bf16x8*>(&Ks32[bb][row][(dk * 8 + hi * 4) ^ sk]);
        sacc[0][kt] = __builtin_amdgcn_mfma_f32_32x32x16_bf16(kf, qf[0][dk], sacc[0][kt], 0, 0, 0);
        sacc[1][kt] = __builtin_amdgcn_mfma_f32_32x32x16_bf16(kf, qf[1][dk], sacc[1][kt], 0, 0, 0);
      }
    }

    // ---- online softmax (q-row = l31; 32 raw scores per qh per lane) ----
    float pm[2];
    #pragma unroll
    for (int qh = 0; qh < 2; ++qh) {
      float t3[12];
      #pragma unroll
      for (int i = 0; i < 10; ++i) {
        const int i0 = 3 * i, i1 = 3 * i + 1, i2 = 3 * i + 2;
        const float a0 = (i0 < 16) ? sacc[qh][0][i0] : sacc[qh][1][i0 - 16];
        const float a1 = (i1 < 16) ? sacc[qh][0][i1] : sacc[qh][1][i1 - 16];
        const float a2 = (i2 < 16) ? sacc[qh][0][i2] : sacc[qh][1][i2 - 16];
        t3[i] = max3f(a0, a1, a2);
      }
      t3[10] = sacc[qh][1][14]; t3[11] = sacc[qh][1][15];
      const float c0 = max3f(t3[0], t3[1], t3[2]), c1 = max3f(t3[3], t3[4], t3[5]);
      const float c2 = max3f(t3[6], t3[7], t3[8]), c3 = max3f(t3[9], t3[10], t3[11]);
      float mx = fmaxf(max3f(c0, c1, c2), c3);
      mx = fmaxf(mx, __shfl_xor(mx, 32));
      pm[qh] = mx * 0.125f;
    }

    float al[2] = {1.f, 1.f};
    const bool noresc = __all(fmaxf(pm[0] - m_run[0], pm[1] - m_run[1]) <= 8.0f);
    if (!noresc) {
      #pragma unroll
      for (int qh = 0; qh < 2; ++qh) {
        const float mnew = fmaxf(m_run[qh], pm[qh]);
        al[qh] = __builtin_amdgcn_exp2f((m_run[qh] - mnew) * L2E);
        m_run[qh] = mnew;
        accO[qh][0] *= al[qh];
        accO[qh][1] *= al[qh];
      }
    }

    u32 pf[2][4][4];
    #pragma unroll
    for (int qh = 0; qh < 2; ++qh) {
      const float C2 = -m_run[qh] * L2E;
      #pragma unroll
      for (int kt = 0; kt < 2; ++kt)
        #pragma unroll
        for (int r2 = 0; r2 < 16; ++r2)
          sacc[qh][kt][r2] = __builtin_amdgcn_exp2f(fmaf(sacc[qh][kt][r2], C1, C2));
      // sum tree
      f32x16 ps = sacc[qh][0] + sacc[qh][1];
      float s8[8];
      #pragma unroll
      for (int i = 0; i < 8; ++i) s8[i] = ps[i] + ps[i + 8];
      float rs = ((s8[0] + s8[1]) + (s8[2] + s8[3])) + ((s8[4] + s8[5]) + (s8[6] + s8[7]));
      rs += __shfl_xor(rs, 32);
      l_run[qh] = fmaf(l_run[qh], al[qh], rs);

      // P fragments: word j of 16-key window = keys (8*hi+2j, 8*hi+2j+1)
#define MAKE_PF(DST, P, B) do {                                            \
      u32 x1 = cvtpk(P[B+0], P[B+1]);                                      \
      u32 y1 = cvtpk(P[B+4], P[B+5]);                                      \
      u32 x2 = cvtpk(P[B+2], P[B+3]);                                      \
      u32 y2 = cvtpk(P[B+6], P[B+7]);                                      \
      auto s1 = __builtin_amdgcn_permlane32_swap(x1, y1, false, false);    \
      auto s2 = __builtin_amdgcn_permlane32_swap(x2, y2, false, false);    \
      DST[0] = (u32)s1[0]; DST[1] = (u32)s2[0];                            \
      DST[2] = (u32)s1[1]; DST[3] = (u32)s2[1];                            \
    } while (0)
      MAKE_PF(pf[qh][0], sacc[qh][0], 0);
      MAKE_PF(pf[qh][1], sacc[qh][0], 8);
      MAKE_PF(pf[qh][2], sacc[qh][1], 0);
      MAKE_PF(pf[qh][3], sacc[qh][1], 8);
#undef MAKE_PF
    }

    // ---- O^T += V^T * P^T ; each V fragment feeds both q-halves ----
    #pragma unroll
    for (int dt = 0; dt < 2; ++dt) {
      const int row = dt * 32 + l31;
      const int sk = swz4(row);
      #pragma unroll
      for (int kf = 0; kf < 4; ++kf) {
        bf16x8 vf = *reinterpret_cast<const bf16x8*>(&Vt32[bb][row][(kf * 8 + hi * 4) ^ sk]);
        #pragma unroll
        for (int qh = 0; qh < 2; ++qh) {
          union { u32 u[4]; bf16x8 v; } pu;
          pu.u[0] = pf[qh][kf][0]; pu.u[1] = pf[qh][kf][1];
          pu.u[2] = pf[qh][kf][2]; pu.u[3] = pf[qh][kf][3];
          accO[qh][dt] = __builtin_amdgcn_mfma_f32_32x32x16_bf16(vf, pu.v, accO[qh][dt], 0, 0, 0);
        }
      }
    }

    if (t < SEQ / 64 - 1) store_t(bb ^ 1);
    __syncthreads();
  }

  // ---- write O ----
  #pragma unroll
  for (int qh = 0; qh < 2; ++qh) {
    const float inv = 1.f / l_run[qh];
    const size_t rowbase = (size_t)(q0 + qh * 32 + l31) * DIM + headoff;
    #pragma unroll
    for (int dt = 0; dt < 2; ++dt)
      #pragma unroll
      for (int g = 0; g < 4; ++g) {
        ushort4 o;
        o.x = f2bfu(accO[qh][dt][g * 4 + 0] * inv);
        o.y = f2bfu(accO[qh][dt][g * 4 + 1] * inv);
        o.z = f2bfu(accO[qh][dt][g * 4 + 2] * inv);
        o.w = f2bfu(accO[qh][dt][g * 4 + 3] * inv);
        *reinterpret_cast<ushort4*>(&Ob[rowbase + dt * 32 + g * 8 + hi * 4]) = o;
      }
  }
}

// ---------------------------------------------------------------------------
extern "C" void kernel_launch(void* const* d_in, const int* in_sizes, int n_in,
                              void* d_out, int out_size, void* d_ws, size_t ws_size,
                              hipStream_t stream)
{
  const float* q  = (const float*)d_in[0];
  const float* k  = (const float*)d_in[1];
  const float* v  = (const float*)d_in[2];
  const float* wq = (const float*)d_in[3];
  const float* bq = (const float*)d_in[4];
  const float* wk = (const float*)d_in[5];
  const float* bk = (const float*)d_in[6];
  const float* wv = (const float*)d_in[7];
  const float* bv = (const float*)d_in[8];
  const float* wo = (const float*)d_in[9];
  const float* bo = (const float*)d_in[10];

  const int M = BATCH * SEQ, N = DIM, K = DIM;

  __hip_bfloat16* Qb = (__hip_bfloat16*)d_ws;
  __hip_bfloat16* Kb = Qb + (size_t)M * N;
  __hip_bfloat16* Vb = Kb + (size_t)M * N;
  __hip_bfloat16* Ob = Vb + (size_t)M * N;

  gemm_bias<float, __hip_bfloat16><<<512, 256, 0, stream>>>(q, wq, bq, Qb, M, N, K);
  gemm_bias<float, __hip_bfloat16><<<512, 256, 0, stream>>>(k, wk, bk, Kb, M, N, K);
  gemm_bias<float, __hip_bfloat16><<<512, 256, 0, stream>>>(v, wv, bv, Vb, M, N, K);

  flash_attn<<<512, 256, 0, stream>>>(Qb, Kb, Vb, Ob);

  gemm_bias<__hip_bfloat16, float><<<512, 256, 0, stream>>>(Ob, wo, bo, (float*)d_out, M, N, K);
}

// Round 5
// 210.524 us; speedup vs baseline: 2.3859x; 1.4960x over previous
//
#include <hip/hip_runtime.h>
#include <hip/hip_bf16.h>

#define BATCH 4
#define SEQ   2048
#define DIM   1024
#define NHEAD 16
#define HDIM  64

typedef __bf16    bf16x8 __attribute__((ext_vector_type(8)));
typedef float     f32x16 __attribute__((ext_vector_type(16)));
typedef unsigned  u32;

__device__ __forceinline__ unsigned short f2bfu(float x) {
  union { __hip_bfloat16 b; unsigned short u; } c; c.b = __float2bfloat16(x); return c.u;
}
__device__ __forceinline__ u32 cvtpk(float lo, float hi) {
  u32 r; asm("v_cvt_pk_bf16_f32 %0, %1, %2" : "=v"(r) : "v"(lo), "v"(hi)); return r;
}
__device__ __forceinline__ float max3f(float a, float b, float c) {
  float r; asm("v_max3_f32 %0, %1, %2, %3" : "=v"(r) : "v"(a), "v"(b), "v"(c)); return r;
}
__device__ __forceinline__ int swz4(int row) {
  return ((row & 7) ^ ((row >> 3) & 7)) << 2;
}

// async 16B global->LDS (linear LDS dest: wave-uniform base + lane*16)
#define GLDS16(GP, LP)                                                         \
  __builtin_amdgcn_global_load_lds(                                            \
      (const __attribute__((address_space(1))) void*)(GP),                     \
      (__attribute__((address_space(3))) void*)(LP), 16, 0, 0)

// ---------------------------------------------------------------------------
// Weight transpose+convert: Wt[n][k] = bf16(W[k][n]). 64x64 tile per block.
// ---------------------------------------------------------------------------
__global__ __launch_bounds__(256)
void wtrans(const float* __restrict__ w0, const float* __restrict__ w1,
            const float* __restrict__ w2,
            __hip_bfloat16* __restrict__ t0, __hip_bfloat16* __restrict__ t1,
            __hip_bfloat16* __restrict__ t2)
{
  __shared__ float T[64][68];
  const int mat  = blockIdx.x >> 8;
  const int tile = blockIdx.x & 255;
  const float* W = mat == 0 ? w0 : (mat == 1 ? w1 : w2);
  __hip_bfloat16* Wt = mat == 0 ? t0 : (mat == 1 ? t1 : t2);
  const int k0 = (tile >> 4) * 64, n0 = (tile & 15) * 64;
  const int tid = threadIdx.x;
  const int r = tid >> 2, cq = (tid & 3) * 16;
  #pragma unroll
  for (int j = 0; j < 4; ++j) {
    const float4 v = *reinterpret_cast<const float4*>(&W[(size_t)(k0 + r) * DIM + n0 + cq + j * 4]);
    T[r][cq + j * 4 + 0] = v.x; T[r][cq + j * 4 + 1] = v.y;
    T[r][cq + j * 4 + 2] = v.z; T[r][cq + j * 4 + 3] = v.w;
  }
  __syncthreads();
  u32 o[8];
  #pragma unroll
  for (int j = 0; j < 8; ++j)
    o[j] = cvtpk(T[cq + 2 * j][r], T[cq + 2 * j + 1][r]);
  *reinterpret_cast<uint4*>(&Wt[(size_t)(n0 + r) * DIM + k0 + cq + 0]) = make_uint4(o[0], o[1], o[2], o[3]);
  *reinterpret_cast<uint4*>(&Wt[(size_t)(n0 + r) * DIM + k0 + cq + 8]) = make_uint4(o[4], o[5], o[6], o[7]);
}

// ---------------------------------------------------------------------------
// m97-style GEMM: C[M=8192,N=1024] = A[M,1024] * Wt^T + bias.
// A staged via global_load_lds (fp32 or bf16 payload), Wt (bf16 [N][K]) via
// global_load_lds. Source-side XOR swizzle, swizzled fragment reads.
// 128x128 tile, BK=64, 4 waves 2x2 of 64x64, 32x32x16 MFMA.
// ---------------------------------------------------------------------------
template<typename TIN, typename TOUT, int NSEG>
__global__ __launch_bounds__(256, 2)
void gemm_glds(const TIN* __restrict__ A0, const TIN* __restrict__ A1, const TIN* __restrict__ A2,
               const __hip_bfloat16* __restrict__ W0, const __hip_bfloat16* __restrict__ W1,
               const __hip_bfloat16* __restrict__ W2,
               const float* __restrict__ b0, const float* __restrict__ b1, const float* __restrict__ b2,
               TOUT* __restrict__ C0, TOUT* __restrict__ C1, TOUT* __restrict__ C2)
{
  extern __shared__ char smem[];
  constexpr bool AF32 = (sizeof(TIN) == 4);
  constexpr int ABYTES = 128 * 64 * sizeof(TIN);
  constexpr int K = 1024;

  const int seg = (NSEG == 1) ? 0 : (blockIdx.x >> 9);
  const int idb = (NSEG == 1) ? blockIdx.x : (blockIdx.x & 511);
  const TIN* A = seg == 0 ? A0 : (seg == 1 ? A1 : A2);
  const __hip_bfloat16* Wt = seg == 0 ? W0 : (seg == 1 ? W1 : W2);
  const float* bias = seg == 0 ? b0 : (seg == 1 ? b1 : b2);
  TOUT* C = seg == 0 ? C0 : (seg == 1 ? C1 : C2);

  const int xcd = idb & 7, rr = idb >> 3;
  const int bx = rr & 7, by = xcd + 8 * (rr >> 3);
  const int m0 = by * 128, n0 = bx * 128;

  const int tid = threadIdx.x, lane = tid & 63, w = tid >> 6;
  const int l31 = lane & 31, hi = lane >> 5;
  const int wm = w >> 1, wn = w & 1;

  f32x16 acc[2][2] = {};

  // ---- staging source pointers (t=0), incremented each K-step ----
  constexpr int NA = AF32 ? 8 : 4;
  const TIN* aptr[NA];
  #pragma unroll
  for (int i = 0; i < NA; ++i) {
    if constexpr (AF32) {
      const int off = (w * 8 + i) * 1024 + lane * 16;
      const int r = off >> 8;
      const int s = (off >> 4) & 15;
      const int e2 = ((r & 7) << 1) | ((r >> 3) & 1);
      aptr[i] = A + (size_t)(m0 + r) * K + (s ^ e2) * 4;
    } else {
      const int off = (w * 4 + i) * 1024 + lane * 16;
      const int r = off >> 7;
      const int s = (off >> 4) & 7;
      aptr[i] = A + (size_t)(m0 + r) * K + (s ^ (r & 7)) * 8;
    }
  }
  const __hip_bfloat16* bptr[4];
  #pragma unroll
  for (int i = 0; i < 4; ++i) {
    const int off = (w * 4 + i) * 1024 + lane * 16;
    const int r = off >> 7;
    const int s = (off >> 4) & 7;
    bptr[i] = Wt + (size_t)(n0 + r) * K + (s ^ (r & 7)) * 8;
  }

  // ---- t-invariant LDS read byte-offsets ----
  int aoff[4][2], boff[4][2];
  #pragma unroll
  for (int kk = 0; kk < 4; ++kk) {
    #pragma unroll
    for (int mi = 0; mi < 2; ++mi) {
      const int r = wm * 64 + mi * 32 + l31;
      if constexpr (AF32) {
        const int e2 = ((r & 7) << 1) | ((r >> 3) & 1);
        aoff[kk][mi] = r * 256 + (((kk * 4 + hi * 2) ^ e2) << 4);
      } else {
        aoff[kk][mi] = r * 128 + (((kk * 2 + hi) ^ (r & 7)) << 4);
      }
    }
    #pragma unroll
    for (int ni = 0; ni < 2; ++ni) {
      const int c = wn * 64 + ni * 32 + l31;
      boff[kk][ni] = c * 128 + (((kk * 2 + hi) ^ (c & 7)) << 4);
    }
  }

  for (int t = 0; t < 16; ++t) {
    // ---- async stage A+B tile ----
    #pragma unroll
    for (int i = 0; i < NA; ++i) {
      GLDS16(aptr[i], smem + (w * NA + i) * 1024);
      aptr[i] += 64;
    }
    #pragma unroll
    for (int i = 0; i < 4; ++i) {
      GLDS16(bptr[i], smem + ABYTES + (w * 4 + i) * 1024);
      bptr[i] += 64;
    }
    __syncthreads();   // drains vmcnt -> LDS tile ready

    #pragma unroll
    for (int kk = 0; kk < 4; ++kk) {
      bf16x8 af[2], bfv[2];
      #pragma unroll
      for (int mi = 0; mi < 2; ++mi) {
        if constexpr (AF32) {
          const float4 f0 = *reinterpret_cast<const float4*>(smem + aoff[kk][mi]);
          const float4 f1 = *reinterpret_cast<const float4*>(smem + (aoff[kk][mi] ^ 16));
          union { u32 u[4]; bf16x8 v; } uu;
          uu.u[0] = cvtpk(f0.x, f0.y); uu.u[1] = cvtpk(f0.z, f0.w);
          uu.u[2] = cvtpk(f1.x, f1.y); uu.u[3] = cvtpk(f1.z, f1.w);
          af[mi] = uu.v;
        } else {
          af[mi] = *reinterpret_cast<const bf16x8*>(smem + aoff[kk][mi]);
        }
      }
      #pragma unroll
      for (int ni = 0; ni < 2; ++ni)
        bfv[ni] = *reinterpret_cast<const bf16x8*>(smem + ABYTES + boff[kk][ni]);
      __builtin_amdgcn_s_setprio(1);
      #pragma unroll
      for (int mi = 0; mi < 2; ++mi)
        #pragma unroll
        for (int ni = 0; ni < 2; ++ni)
          acc[mi][ni] = __builtin_amdgcn_mfma_f32_32x32x16_bf16(af[mi], bfv[ni], acc[mi][ni], 0, 0, 0);
      __builtin_amdgcn_s_setprio(0);
    }
    __syncthreads();   // all reads done before next stage overwrites
  }

  // epilogue: D col = lane&31, row = (r&3) + 8*(r>>2) + 4*hi
  #pragma unroll
  for (int ni = 0; ni < 2; ++ni) {
    const int col = n0 + wn * 64 + ni * 32 + l31;
    const float bv = bias[col];
    #pragma unroll
    for (int mi = 0; mi < 2; ++mi) {
      #pragma unroll
      for (int g = 0; g < 4; ++g)
        #pragma unroll
        for (int e = 0; e < 4; ++e) {
          const int row = m0 + wm * 64 + mi * 32 + g * 8 + hi * 4 + e;
          const float val = acc[mi][ni][g * 4 + e] + bv;
          if constexpr (sizeof(TOUT) == 2)
            C[(size_t)row * DIM + col] = __float2bfloat16(val);
          else
            C[(size_t)row * DIM + col] = val;
        }
    }
  }
}

// ---------------------------------------------------------------------------
// Flash attention (round-4 verified structure + s_setprio around MFMA).
// ---------------------------------------------------------------------------
__global__ __launch_bounds__(256, 2)
void flash_attn(const __hip_bfloat16* __restrict__ Qb,
                const __hip_bfloat16* __restrict__ Kb,
                const __hip_bfloat16* __restrict__ Vb,
                __hip_bfloat16* __restrict__ Ob)
{
  __shared__ __align__(16) u32 Ks32[2][64][32];
  __shared__ __align__(16) u32 Vt32[2][64][32];

  const int id  = blockIdx.x;
  const int xcd = id & 7;
  const int r_  = id >> 3;
  const int qb  = r_ & 7;
  const int hh  = (r_ >> 3) & 1;
  const int b   = r_ >> 4;
  const int h   = xcd + 8 * hh;

  const int tid = threadIdx.x, lane = tid & 63, wv = tid >> 6;
  const int l31 = lane & 31, hi = lane >> 5;

  const size_t headoff = (size_t)h * HDIM;
  const int q0 = b * SEQ + qb * 256 + wv * 64;

  bf16x8 qf[2][4];
  #pragma unroll
  for (int qh = 0; qh < 2; ++qh)
    #pragma unroll
    for (int dk = 0; dk < 4; ++dk)
      qf[qh][dk] = *reinterpret_cast<const bf16x8*>(
        &Qb[(size_t)(q0 + qh * 32 + l31) * DIM + headoff + dk * 16 + hi * 8]);

  f32x16 accO[2][2] = {};
  float m_run[2] = {-1e30f, -1e30f}, l_run[2] = {0.f, 0.f};

  const int skey = tid >> 2;
  const int sdq  = tid & 3;
  const int vkp  = tid >> 3;
  const int vdb  = tid & 7;
  const size_t kbase = (size_t)b * SEQ * DIM + headoff;

  uint4 kst[2], vst[2];
  auto load_t = [&](int t) {
    const int kb = t * 64;
    const __hip_bfloat16* kp_ = &Kb[kbase + (size_t)(kb + skey) * DIM + sdq * 16];
    kst[0] = *reinterpret_cast<const uint4*>(kp_);
    kst[1] = *reinterpret_cast<const uint4*>(kp_ + 8);
    const __hip_bfloat16* vp_ = &Vb[kbase + (size_t)(kb + vkp * 2) * DIM + vdb * 8];
    vst[0] = *reinterpret_cast<const uint4*>(vp_);
    vst[1] = *reinterpret_cast<const uint4*>(vp_ + DIM);
  };
  auto store_t = [&](int bb) {
    const int sk = swz4(skey);
    *reinterpret_cast<uint4*>(&Ks32[bb][skey][(sdq * 8 + 0) ^ sk]) = kst[0];
    *reinterpret_cast<uint4*>(&Ks32[bb][skey][(sdq * 8 + 4) ^ sk]) = kst[1];
    const unsigned short* a  = (const unsigned short*)&vst[0];
    const unsigned short* bv = (const unsigned short*)&vst[1];
    #pragma unroll
    for (int j = 0; j < 8; ++j) {
      const int row = vdb * 8 + j;
      Vt32[bb][row][vkp ^ swz4(row)] = (u32)a[j] | ((u32)bv[j] << 16);
    }
  };

  load_t(0); store_t(0); __syncthreads();

  const float C1  = 0.125f * 1.44269504f;
  const float L2E = 1.44269504f;

  for (int t = 0; t < SEQ / 64; ++t) {
    const int bb = t & 1;
    if (t < SEQ / 64 - 1) load_t(t + 1);

    f32x16 sacc[2][2] = {};
    __builtin_amdgcn_s_setprio(1);
    #pragma unroll
    for (int kt = 0; kt < 2; ++kt) {
      const int row = kt * 32 + l31;
      const int sk = swz4(row);
      #pragma unroll
      for (int dk = 0; dk < 4; ++dk) {
        bf16x8 kf = *reinterpret_cast<const bf16x8*>(&Ks32[bb][row][(dk * 8 + hi * 4) ^ sk]);
        sacc[0][kt] = __builtin_amdgcn_mfma_f32_32x32x16_bf16(kf, qf[0][dk], sacc[0][kt], 0, 0, 0);
        sacc[1][kt] = __builtin_amdgcn_mfma_f32_32x32x16_bf16(kf, qf[1][dk], sacc[1][kt], 0, 0, 0);
      }
    }
    __builtin_amdgcn_s_setprio(0);

    float pm[2];
    #pragma unroll
    for (int qh = 0; qh < 2; ++qh) {
      float t3[12];
      #pragma unroll
      for (int i = 0; i < 10; ++i) {
        const int i0 = 3 * i, i1 = 3 * i + 1, i2 = 3 * i + 2;
        const float a0 = (i0 < 16) ? sacc[qh][0][i0] : sacc[qh][1][i0 - 16];
        const float a1 = (i1 < 16) ? sacc[qh][0][i1] : sacc[qh][1][i1 - 16];
        const float a2 = (i2 < 16) ? sacc[qh][0][i2] : sacc[qh][1][i2 - 16];
        t3[i] = max3f(a0, a1, a2);
      }
      t3[10] = sacc[qh][1][14]; t3[11] = sacc[qh][1][15];
      const float c0 = max3f(t3[0], t3[1], t3[2]), c1 = max3f(t3[3], t3[4], t3[5]);
      const float c2 = max3f(t3[6], t3[7], t3[8]), c3 = max3f(t3[9], t3[10], t3[11]);
      float mx = fmaxf(max3f(c0, c1, c2), c3);
      mx = fmaxf(mx, __shfl_xor(mx, 32));
      pm[qh] = mx * 0.125f;
    }

    float al[2] = {1.f, 1.f};
    const bool noresc = __all(fmaxf(pm[0] - m_run[0], pm[1] - m_run[1]) <= 8.0f);
    if (!noresc) {
      #pragma unroll
      for (int qh = 0; qh < 2; ++qh) {
        const float mnew = fmaxf(m_run[qh], pm[qh]);
        al[qh] = __builtin_amdgcn_exp2f((m_run[qh] - mnew) * L2E);
        m_run[qh] = mnew;
        accO[qh][0] *= al[qh];
        accO[qh][1] *= al[qh];
      }
    }

    u32 pf[2][4][4];
    #pragma unroll
    for (int qh = 0; qh < 2; ++qh) {
      const float C2 = -m_run[qh] * L2E;
      #pragma unroll
      for (int kt = 0; kt < 2; ++kt)
        #pragma unroll
        for (int r2 = 0; r2 < 16; ++r2)
          sacc[qh][kt][r2] = __builtin_amdgcn_exp2f(fmaf(sacc[qh][kt][r2], C1, C2));
      f32x16 ps = sacc[qh][0] + sacc[qh][1];
      float s8[8];
      #pragma unroll
      for (int i = 0; i < 8; ++i) s8[i] = ps[i] + ps[i + 8];
      float rs = ((s8[0] + s8[1]) + (s8[2] + s8[3])) + ((s8[4] + s8[5]) + (s8[6] + s8[7]));
      rs += __shfl_xor(rs, 32);
      l_run[qh] = fmaf(l_run[qh], al[qh], rs);

#define MAKE_PF(DST, P, B) do {                                            \
      u32 x1 = cvtpk(P[B+0], P[B+1]);                                      \
      u32 y1 = cvtpk(P[B+4], P[B+5]);                                      \
      u32 x2 = cvtpk(P[B+2], P[B+3]);                                      \
      u32 y2 = cvtpk(P[B+6], P[B+7]);                                      \
      auto s1 = __builtin_amdgcn_permlane32_swap(x1, y1, false, false);    \
      auto s2 = __builtin_amdgcn_permlane32_swap(x2, y2, false, false);    \
      DST[0] = (u32)s1[0]; DST[1] = (u32)s2[0];                            \
      DST[2] = (u32)s1[1]; DST[3] = (u32)s2[1];                            \
    } while (0)
      MAKE_PF(pf[qh][0], sacc[qh][0], 0);
      MAKE_PF(pf[qh][1], sacc[qh][0], 8);
      MAKE_PF(pf[qh][2], sacc[qh][1], 0);
      MAKE_PF(pf[qh][3], sacc[qh][1], 8);
#undef MAKE_PF
    }

    __builtin_amdgcn_s_setprio(1);
    #pragma unroll
    for (int dt = 0; dt < 2; ++dt) {
      const int row = dt * 32 + l31;
      const int sk = swz4(row);
      #pragma unroll
      for (int kf = 0; kf < 4; ++kf) {
        bf16x8 vf = *reinterpret_cast<const bf16x8*>(&Vt32[bb][row][(kf * 8 + hi * 4) ^ sk]);
        #pragma unroll
        for (int qh = 0; qh < 2; ++qh) {
          union { u32 u[4]; bf16x8 v; } pu;
          pu.u[0] = pf[qh][kf][0]; pu.u[1] = pf[qh][kf][1];
          pu.u[2] = pf[qh][kf][2]; pu.u[3] = pf[qh][kf][3];
          accO[qh][dt] = __builtin_amdgcn_mfma_f32_32x32x16_bf16(vf, pu.v, accO[qh][dt], 0, 0, 0);
        }
      }
    }
    __builtin_amdgcn_s_setprio(0);

    if (t < SEQ / 64 - 1) store_t(bb ^ 1);
    __syncthreads();
  }

  #pragma unroll
  for (int qh = 0; qh < 2; ++qh) {
    const float inv = 1.f / l_run[qh];
    const size_t rowbase = (size_t)(q0 + qh * 32 + l31) * DIM + headoff;
    #pragma unroll
    for (int dt = 0; dt < 2; ++dt)
      #pragma unroll
      for (int g = 0; g < 4; ++g) {
        ushort4 o;
        o.x = f2bfu(accO[qh][dt][g * 4 + 0] * inv);
        o.y = f2bfu(accO[qh][dt][g * 4 + 1] * inv);
        o.z = f2bfu(accO[qh][dt][g * 4 + 2] * inv);
        o.w = f2bfu(accO[qh][dt][g * 4 + 3] * inv);
        *reinterpret_cast<ushort4*>(&Ob[rowbase + dt * 32 + g * 8 + hi * 4]) = o;
      }
  }
}

// ---------------------------------------------------------------------------
extern "C" void kernel_launch(void* const* d_in, const int* in_sizes, int n_in,
                              void* d_out, int out_size, void* d_ws, size_t ws_size,
                              hipStream_t stream)
{
  const float* q  = (const float*)d_in[0];
  const float* k  = (const float*)d_in[1];
  const float* v  = (const float*)d_in[2];
  const float* wq = (const float*)d_in[3];
  const float* bq = (const float*)d_in[4];
  const float* wk = (const float*)d_in[5];
  const float* bk = (const float*)d_in[6];
  const float* wv = (const float*)d_in[7];
  const float* bv = (const float*)d_in[8];
  const float* wo = (const float*)d_in[9];
  const float* bo = (const float*)d_in[10];

  const size_t MN = (size_t)BATCH * SEQ * DIM;   // 8388608
  const size_t KK = (size_t)DIM * DIM;           // 1048576

  __hip_bfloat16* Qb = (__hip_bfloat16*)d_ws;
  __hip_bfloat16* Kb = Qb + MN;
  __hip_bfloat16* Vb = Kb + MN;
  __hip_bfloat16* S3 = Vb + MN;     // 4th 16MB slot
  __hip_bfloat16* WtQ = S3;         // weights live here until attention
  __hip_bfloat16* WtK = S3 + KK;
  __hip_bfloat16* WtV = S3 + 2 * KK;
  __hip_bfloat16* Ob  = S3;         // attention output overwrites Wt (dead)
  __hip_bfloat16* WtO = (__hip_bfloat16*)d_ws;  // into Qb slot after attention

  wtrans<<<768, 256, 0, stream>>>(wq, wk, wv, WtQ, WtK, WtV);

  gemm_glds<float, __hip_bfloat16, 3><<<1536, 256, 49152, stream>>>(
      q, k, v, WtQ, WtK, WtV, bq, bk, bv, Qb, Kb, Vb);

  flash_attn<<<512, 256, 0, stream>>>(Qb, Kb, Vb, Ob);

  wtrans<<<256, 256, 0, stream>>>(wo, wo, wo, WtO, WtO, WtO);

  gemm_glds<__hip_bfloat16, float, 1><<<512, 256, 32768, stream>>>(
      Ob, Ob, Ob, WtO, WtO, WtO, bo, bo, bo,
      (float*)d_out, (float*)d_out, (float*)d_out);
}